// Round 1
// baseline (44247.998 us; speedup 1.0000x reference)
//
#include <hip/hip_runtime.h>
#include <math.h>

// ---------------------------------------------------------------------------
// Problem constants (PTB LN-LSTM stack): B=128, T=100, E=128, F=700, S=400,
// V=10000.  Recurrence: cell0(x,fh)->slow(fh,sh)->cell1(sh,fh) per step,
// then logits = hist[B*T,F] @ Wout[F,V] + bout.
// ---------------------------------------------------------------------------

#define B_ 128
#define T_ 100
#define E_ 128
#define F_ 700
#define S_ 400
#define V_ 10000

__device__ __forceinline__ float sigm(float x) { return 1.0f / (1.0f + expf(-x)); }

// Block-wide sum over 256 threads (4 waves of 64), broadcast to all threads.
__device__ __forceinline__ float blockSum(float v, volatile float* red) {
    #pragma unroll
    for (int off = 32; off > 0; off >>= 1) v += __shfl_down(v, off, 64);
    int wid = threadIdx.x >> 6;
    int lane = threadIdx.x & 63;
    __syncthreads();                 // protect red[] reuse across calls
    if (lane == 0) red[wid] = v;
    __syncthreads();
    return red[0] + red[1] + red[2] + red[3];
}

// ---------------------------------------------------------------------------
// Recurrent GEMM:  Z[M=128, N] = [A1 | A2] @ W + bias
//   A row m: A1[m*lda1 + k] for k<K1, else A2[m*lda2 + (k-K1)]
//   W is [K1+K2, N] row-major.
// Tile: BM=32, BN=64, BK=32; 256 threads; 2x4 microtile.
// ---------------------------------------------------------------------------
__global__ __launch_bounds__(256) void gemm_cat(
    const float* __restrict__ A1, int lda1, int K1,
    const float* __restrict__ A2, int lda2, int K2,
    const float* __restrict__ W, const float* __restrict__ bias,
    float* __restrict__ Z, int N)
{
    __shared__ float As[32][34];   // [k][row], stride 34 (even -> float2 aligned)
    __shared__ float Ws[32][64];   // [k][col]
    const int K = K1 + K2;
    const int row0 = blockIdx.y * 32;
    const int col0 = blockIdx.x * 64;
    const int tid = threadIdx.x;
    const int tr = tid >> 4;   // 0..15 -> rows 2*tr, 2*tr+1
    const int tc = tid & 15;   // cols 4*tc .. 4*tc+3

    float acc[2][4] = {{0.f,0.f,0.f,0.f},{0.f,0.f,0.f,0.f}};

    for (int k0 = 0; k0 < K; k0 += 32) {
        // A tile: 32 rows x 32 k  (transposed into As[k][row])
        #pragma unroll
        for (int i = 0; i < 4; ++i) {
            int idx = tid + i * 256;
            int r = idx >> 5, kk = idx & 31;
            int kg = k0 + kk;
            int row = row0 + r;
            float v = 0.f;
            if (kg < K) {
                v = (kg < K1) ? A1[(long long)row * lda1 + kg]
                              : A2[(long long)row * lda2 + (kg - K1)];
            }
            As[kk][r] = v;
        }
        // W tile: 32 k x 64 cols
        #pragma unroll
        for (int i = 0; i < 8; ++i) {
            int idx = tid + i * 256;
            int kk = idx >> 6, c = idx & 63;
            int kg = k0 + kk, cg = col0 + c;
            Ws[kk][c] = (kg < K && cg < N) ? W[(long long)kg * N + cg] : 0.f;
        }
        __syncthreads();
        #pragma unroll
        for (int kk = 0; kk < 32; ++kk) {
            float2 a = *(const float2*)&As[kk][tr * 2];
            float4 w = *(const float4*)&Ws[kk][tc * 4];
            acc[0][0] += a.x * w.x; acc[0][1] += a.x * w.y;
            acc[0][2] += a.x * w.z; acc[0][3] += a.x * w.w;
            acc[1][0] += a.y * w.x; acc[1][1] += a.y * w.y;
            acc[1][2] += a.y * w.z; acc[1][3] += a.y * w.w;
        }
        __syncthreads();
    }
    #pragma unroll
    for (int r = 0; r < 2; ++r) {
        int row = row0 + tr * 2 + r;
        #pragma unroll
        for (int j = 0; j < 4; ++j) {
            int col = col0 + tc * 4 + j;
            if (col < N) Z[(long long)row * N + col] = acc[r][j] + bias[col];
        }
    }
}

// ---------------------------------------------------------------------------
// Fused LN4 + gates + c-LN + zoneout for one cell.  One block per batch row.
//   z row layout: [i | j | f | o], each chunk of size F.
//   new_c = c*sigmoid(f_ln + 1) + sigmoid(i_ln)*tanh(j_ln)
//   new_h = tanh(LN(new_c)*gc+bc) * sigmoid(o_ln)
//   h <- 0.9*new_h + 0.1*h ;  c <- 0.5*new_c + 0.5*c
// ---------------------------------------------------------------------------
#define MAXU 3   // ceil(700/256)
__global__ __launch_bounds__(256) void cell_pw(
    const float* __restrict__ z, int F,
    const float* __restrict__ gg, const float* __restrict__ bg,
    const float* __restrict__ gc, const float* __restrict__ bc,
    float* __restrict__ h, float* __restrict__ c,
    float* __restrict__ hist, long long histRowStride)
{
    __shared__ float red[8];
    const int b = blockIdx.x;
    const int tid = threadIdx.x;
    const float* zr = z + (long long)b * 4 * F;
    float* hr = h + (long long)b * F;
    float* cr = c + (long long)b * F;

    // phase 1: per-gate mean / var
    float s[4] = {0,0,0,0}, q[4] = {0,0,0,0};
    for (int u = tid; u < F; u += 256) {
        #pragma unroll
        for (int g = 0; g < 4; ++g) { float v = zr[g * F + u]; s[g] += v; q[g] += v * v; }
    }
    float mu[4], rs[4];
    #pragma unroll
    for (int g = 0; g < 4; ++g) {
        float S = blockSum(s[g], red);
        float Q = blockSum(q[g], red);
        mu[g] = S / F;
        float var = Q / F - mu[g] * mu[g];
        rs[g] = rsqrtf(var + 1e-5f);
    }

    // phase 2: gates -> new_c (keep per-thread), accumulate c stats
    float nc[MAXU], og[MAXU], ho[MAXU], co[MAXU];
    float cs = 0.f, cq = 0.f;
    int nu = 0;
    for (int u = tid; u < F; u += 256) {
        float zi = (zr[u]         - mu[0]) * rs[0] * gg[u]         + bg[u];
        float zj = (zr[F + u]     - mu[1]) * rs[1] * gg[F + u]     + bg[F + u];
        float zf = (zr[2 * F + u] - mu[2]) * rs[2] * gg[2 * F + u] + bg[2 * F + u];
        float zo = (zr[3 * F + u] - mu[3]) * rs[3] * gg[3 * F + u] + bg[3 * F + u];
        float cold = cr[u];
        float ncv = cold * sigm(zf + 1.0f) + sigm(zi) * tanhf(zj);
        nc[nu] = ncv;
        og[nu] = sigm(zo);
        co[nu] = cold;
        ho[nu] = hr[u];
        cs += ncv; cq += ncv * ncv;
        ++nu;
    }
    float CS = blockSum(cs, red);
    float CQ = blockSum(cq, red);
    float muc = CS / F;
    float rsc = rsqrtf(CQ / F - muc * muc + 1e-5f);

    // phase 3: h/c outputs with zoneout
    nu = 0;
    for (int u = tid; u < F; u += 256) {
        float nh = tanhf((nc[nu] - muc) * rsc * gc[u] + bc[u]) * og[nu];
        float hout = 0.9f * nh + 0.1f * ho[nu];
        float cout = 0.5f * nc[nu] + 0.5f * co[nu];
        hr[u] = hout;
        cr[u] = cout;
        if (hist) hist[(long long)b * histRowStride + u] = hout;
        ++nu;
    }
}

// ---------------------------------------------------------------------------
// Output projection:  C[M=12800, N=10000] = A[M,700] @ W[700,N] + bias
// Tile: 128x128, BK=16, 256 threads, 8x8 microtile.
// ---------------------------------------------------------------------------
__global__ __launch_bounds__(256) void gemm_out(
    const float* __restrict__ A, const float* __restrict__ W,
    const float* __restrict__ bias, float* __restrict__ C,
    int M, int N, int K)
{
    __shared__ float As[16][132];   // [k][row]
    __shared__ float Ws[16][132];   // [k][col]
    const int row0 = blockIdx.y * 128;
    const int col0 = blockIdx.x * 128;
    const int tid = threadIdx.x;
    const int tr = tid >> 4;   // rows 8*tr ..
    const int tc = tid & 15;   // cols 8*tc ..

    float acc[8][8];
    #pragma unroll
    for (int i = 0; i < 8; ++i)
        #pragma unroll
        for (int j = 0; j < 8; ++j) acc[i][j] = 0.f;

    for (int k0 = 0; k0 < K; k0 += 16) {
        #pragma unroll
        for (int i = 0; i < 8; ++i) {
            int idx = tid + i * 256;
            int r = idx >> 4, kk = idx & 15;
            int kg = k0 + kk;
            As[kk][r] = (kg < K) ? A[(size_t)(row0 + r) * K + kg] : 0.f;
        }
        #pragma unroll
        for (int i = 0; i < 8; ++i) {
            int idx = tid + i * 256;
            int kk = idx >> 7, cc = idx & 127;
            int kg = k0 + kk, cg = col0 + cc;
            Ws[kk][cc] = (kg < K && cg < N) ? W[(size_t)kg * N + cg] : 0.f;
        }
        __syncthreads();
        #pragma unroll
        for (int kk = 0; kk < 16; ++kk) {
            float a[8], w[8];
            *(float4*)&a[0] = *(const float4*)&As[kk][tr * 8];
            *(float4*)&a[4] = *(const float4*)&As[kk][tr * 8 + 4];
            *(float4*)&w[0] = *(const float4*)&Ws[kk][tc * 8];
            *(float4*)&w[4] = *(const float4*)&Ws[kk][tc * 8 + 4];
            #pragma unroll
            for (int i = 0; i < 8; ++i)
                #pragma unroll
                for (int j = 0; j < 8; ++j) acc[i][j] += a[i] * w[j];
        }
        __syncthreads();
    }
    #pragma unroll
    for (int i = 0; i < 8; ++i) {
        int row = row0 + tr * 8 + i;
        if (row >= M) continue;
        #pragma unroll
        for (int j = 0; j < 8; ++j) {
            int col = col0 + tc * 8 + j;
            if (col < N) C[(size_t)row * N + col] = acc[i][j] + bias[col];
        }
    }
}

// Copy final states (fh, fc, sh, sc) to the tail of d_out.
__global__ void copy_states(const float* __restrict__ fh, const float* __restrict__ fc,
                            const float* __restrict__ sh, const float* __restrict__ sc,
                            float* __restrict__ out)
{
    int i = blockIdx.x * 256 + threadIdx.x;
    const int NF = B_ * F_;   // 89600
    const int NS = B_ * S_;   // 51200
    if (i < NF) out[i] = fh[i];
    else if (i < 2 * NF) out[i] = fc[i - NF];
    else if (i < 2 * NF + NS) out[i] = sh[i - 2 * NF];
    else if (i < 2 * NF + 2 * NS) out[i] = sc[i - 2 * NF - NS];
}

extern "C" void kernel_launch(void* const* d_in, const int* in_sizes, int n_in,
                              void* d_out, int out_size, void* d_ws, size_t ws_size,
                              hipStream_t stream) {
    const float* inputs = (const float*)d_in[0];
    const float* W0   = (const float*)d_in[1];
    const float* b0   = (const float*)d_in[2];
    const float* g0   = (const float*)d_in[3];
    const float* bg0  = (const float*)d_in[4];
    const float* gc0  = (const float*)d_in[5];
    const float* bc0  = (const float*)d_in[6];
    const float* W1   = (const float*)d_in[7];
    const float* b1   = (const float*)d_in[8];
    const float* g1   = (const float*)d_in[9];
    const float* bg1  = (const float*)d_in[10];
    const float* gc1  = (const float*)d_in[11];
    const float* bc1  = (const float*)d_in[12];
    const float* WS   = (const float*)d_in[13];
    const float* bS   = (const float*)d_in[14];
    const float* gS   = (const float*)d_in[15];
    const float* bgS  = (const float*)d_in[16];
    const float* gcS  = (const float*)d_in[17];
    const float* bcS  = (const float*)d_in[18];
    const float* Wout = (const float*)d_in[19];
    const float* bout = (const float*)d_in[20];

    float* ws = (float*)d_ws;
    float* fh   = ws;                    // 128*700  = 89600
    float* fc   = fh + B_ * F_;          // 89600
    float* sh   = fc + B_ * F_;          // 51200
    float* sc   = sh + B_ * S_;          // 51200
    float* z    = sc + B_ * S_;          // 128*2800 = 358400
    float* hist = z + B_ * 4 * F_;       // 128*100*700 = 8,960,000

    // zero the recurrent states (fh,fc,sh,sc are contiguous)
    hipMemsetAsync(fh, 0, (size_t)(2 * B_ * F_ + 2 * B_ * S_) * sizeof(float), stream);

    for (int t = 0; t < T_; ++t) {
        // cell 0: x = inputs[:,t,:], h = fh
        gemm_cat<<<dim3(44, 4), 256, 0, stream>>>(
            inputs + (long long)t * E_, T_ * E_, E_, fh, F_, F_, W0, b0, z, 4 * F_);
        cell_pw<<<B_, 256, 0, stream>>>(z, F_, g0, bg0, gc0, bc0, fh, fc, nullptr, 0);
        // slow cell: x = fh(new), h = sh
        gemm_cat<<<dim3(25, 4), 256, 0, stream>>>(
            fh, F_, F_, sh, S_, S_, WS, bS, z, 4 * S_);
        cell_pw<<<B_, 256, 0, stream>>>(z, S_, gS, bgS, gcS, bcS, sh, sc, nullptr, 0);
        // cell 1: x = sh(new), h = fh
        gemm_cat<<<dim3(44, 4), 256, 0, stream>>>(
            sh, S_, S_, fh, F_, F_, W1, b1, z, 4 * F_);
        cell_pw<<<B_, 256, 0, stream>>>(z, F_, g1, bg1, gc1, bc1, fh, fc,
                                        hist + (long long)t * F_, (long long)T_ * F_);
    }

    // logits: hist[12800,700] @ Wout[700,10000] + bout  -> d_out[0 .. 128e6)
    gemm_out<<<dim3(79, 100), 256, 0, stream>>>(
        hist, Wout, bout, (float*)d_out, B_ * T_, V_, F_);

    // final states -> d_out tail
    copy_states<<<1100, 256, 0, stream>>>(
        fh, fc, sh, sc, (float*)d_out + (size_t)B_ * T_ * V_);
}

// Round 5
// 42478.784 us; speedup vs baseline: 1.0416x; 1.0416x over previous
//
#include <hip/hip_runtime.h>
#include <math.h>

// ---------------------------------------------------------------------------
// PTB LN-LSTM stack: B=128, T=100, E=128, F=700, S=400, V=10000.
// Round 5: 3-term bf16-split MFMA recurrence (numerics proven in round 4,
// absmax 0.03125 == f32 baseline). Fixes vs round 4:
//   - wtrans3 writes EVERY [Npad][Kp] element (pads = 0): replays are
//     bit-identical to call 1 even after the harness poisons buffers.
//   - scratch lives in d_ws when ws_size allows (65.7 MB); d_out scratch is
//     only a (fully-written, replay-safe) fallback.
//   - x split 3-way in registers inside rgemm3<XF32=true> (no splitx pass).
// ---------------------------------------------------------------------------

#define B_ 128
#define T_ 100
#define E_ 128
#define F_ 700
#define S_ 400
#define V_ 10000

#define FP_ 704    // F padded to mult of 32
#define SP_ 416    // S padded to mult of 32

using v8s = __attribute__((ext_vector_type(8))) short;   // 8 bf16 (4 VGPR)
using v4f = __attribute__((ext_vector_type(4))) float;   // MFMA acc

__device__ __forceinline__ unsigned short f2bf(float x) {
    unsigned int u = __float_as_uint(x);
    u += 0x7FFFu + ((u >> 16) & 1u);          // round-to-nearest-even
    return (unsigned short)(u >> 16);
}
__device__ __forceinline__ float bf2f(unsigned short h) {
    return __uint_as_float(((unsigned int)h) << 16);
}
__device__ __forceinline__ void split3f(float x, unsigned short& h,
                                        unsigned short& m, unsigned short& l) {
    h = f2bf(x); float r  = x - bf2f(h);
    m = f2bf(r); float r2 = r - bf2f(m);
    l = f2bf(r2);
}
__device__ __forceinline__ float sigm(float x) { return 1.0f / (1.0f + expf(-x)); }

// ---------------------------------------------------------------------------
// W[K][N] f32 -> three bf16 planes Wt{H,M,L}[Npad][Kp], transposed.
// Output-space iteration: EVERY (r, kpos) in the grid is written (pads -> 0),
// so scratch contents are independent of prior buffer state.
// Inverse k-map: kpos<K1 -> k=kpos ; K1<=kpos<K1pad -> pad(0) ;
//                kpos>=K1pad -> k=K1+(kpos-K1pad) (0 if k>=K).
// grid: (Npad/32, Kp/32), 256 threads.
// ---------------------------------------------------------------------------
__global__ __launch_bounds__(256) void wtrans3(
    const float* __restrict__ W, int K, int N,
    unsigned short* __restrict__ WtH, unsigned short* __restrict__ WtM,
    unsigned short* __restrict__ WtL, int Kp, int K1, int K1pad)
{
    __shared__ float t[32][33];
    const int c0 = blockIdx.x * 32, kp0 = blockIdx.y * 32;
    const int tx = threadIdx.x & 31, ty = threadIdx.x >> 5;
    #pragma unroll
    for (int i = 0; i < 4; ++i) {
        int kpos = kp0 + ty + i * 8, c = c0 + tx;
        int k = (kpos < K1) ? kpos
              : (kpos >= K1pad) ? (K1 + (kpos - K1pad)) : -1;
        t[ty + i * 8][tx] = (k >= 0 && k < K && c < N) ? W[(size_t)k * N + c] : 0.f;
    }
    __syncthreads();
    #pragma unroll
    for (int i = 0; i < 4; ++i) {
        int r = c0 + ty + i * 8;              // Wt row == W col
        unsigned short h, m, l;
        split3f(t[tx][ty + i * 8], h, m, l);
        size_t idx = (size_t)r * Kp + kp0 + tx;
        WtH[idx] = h; WtM[idx] = m; WtL[idx] = l;
    }
}

// Single-plane transpose (for Wout): Wt[Npad][Kpad] = bf16(W[K][N])^T.
// Also writes every element in the grid (pads -> 0).
__global__ __launch_bounds__(256) void wtrans(
    const float* __restrict__ W, int K, int N,
    unsigned short* __restrict__ Wt, int Kpad)
{
    __shared__ float t[32][33];
    const int c0 = blockIdx.x * 32, k0 = blockIdx.y * 32;
    const int tx = threadIdx.x & 31, ty = threadIdx.x >> 5;
    #pragma unroll
    for (int i = 0; i < 4; ++i) {
        int k = k0 + ty + i * 8, c = c0 + tx;
        t[ty + i * 8][tx] = (k < K && c < N) ? W[(size_t)k * N + c] : 0.f;
    }
    __syncthreads();
    #pragma unroll
    for (int i = 0; i < 4; ++i) {
        int r = c0 + ty + i * 8;
        Wt[(size_t)r * Kpad + k0 + tx] = f2bf(t[tx][ty + i * 8]);
    }
}

// ---------------------------------------------------------------------------
// Split-precision recurrent MFMA GEMM (no LDS):
//   Z[128,N] = concat(A1,A2)[128,Kp] @ Wt^T + bias (3-plane operands,
//   6 products: hh, hm, mh, hl, lh, mm -> ~2^-26 rel error).
// XF32=true: A1 is raw f32 (the inputs x), split 3-way in registers.
// k-tiles [0, K1pad/32) read A1; rest read A2 (K1pad % 32 == 0).
// 256 thr = 4 waves; wave w owns cols [blk*128 + w*32, +32).
// ---------------------------------------------------------------------------
template <bool XF32>
__global__ __launch_bounds__(256) void rgemm3(
    const float* __restrict__ xA1,
    const unsigned short* __restrict__ A1H, const unsigned short* __restrict__ A1M,
    const unsigned short* __restrict__ A1L, int lda1, int K1pad,
    const unsigned short* __restrict__ A2H, const unsigned short* __restrict__ A2M,
    const unsigned short* __restrict__ A2L, int lda2,
    const unsigned short* __restrict__ WH, const unsigned short* __restrict__ WM,
    const unsigned short* __restrict__ WL, int Kp,
    const float* __restrict__ bias, float* __restrict__ Z, int N)
{
    const int tid = threadIdx.x, lane = tid & 63, wid = tid >> 6;
    const int c0 = blockIdx.x * 128 + wid * 32;
    const int lo = lane & 15, hi = lane >> 4;
    const int NT = Kp / 32;

    v4f acc[8][2];
    #pragma unroll
    for (int m = 0; m < 8; ++m) { acc[m][0] = (v4f)0.f; acc[m][1] = (v4f)0.f; }

    for (int kt = 0; kt < NT; ++kt) {
        const size_t bo0 = (size_t)(c0 + lo) * Kp + kt * 32 + hi * 8;
        const size_t bo1 = bo0 + (size_t)16 * Kp;
        v8s b0h = *(const v8s*)(WH + bo0), b0m = *(const v8s*)(WM + bo0),
            b0l = *(const v8s*)(WL + bo0);
        v8s b1h = *(const v8s*)(WH + bo1), b1m = *(const v8s*)(WM + bo1),
            b1l = *(const v8s*)(WL + bo1);
        const bool s1 = (kt * 32) < K1pad;
        const int ko = s1 ? kt * 32 : kt * 32 - K1pad;
        #pragma unroll
        for (int m = 0; m < 8; ++m) {
            v8s ah, am, al;
            if (XF32 && s1) {
                const float* p = xA1 + (size_t)(m * 16 + lo) * lda1 + ko + hi * 8;
                float v[8];
                *(float4*)(v)     = *(const float4*)(p);
                *(float4*)(v + 4) = *(const float4*)(p + 4);
                #pragma unroll
                for (int j = 0; j < 8; ++j) {
                    unsigned short H, M, L;
                    split3f(v[j], H, M, L);
                    ah[j] = (short)H; am[j] = (short)M; al[j] = (short)L;
                }
            } else {
                const unsigned short* pH = s1 ? A1H : A2H;
                const unsigned short* pM = s1 ? A1M : A2M;
                const unsigned short* pL = s1 ? A1L : A2L;
                const int lda = s1 ? lda1 : lda2;
                size_t ao = (size_t)(m * 16 + lo) * lda + ko + hi * 8;
                ah = *(const v8s*)(pH + ao);
                am = *(const v8s*)(pM + ao);
                al = *(const v8s*)(pL + ao);
            }
            acc[m][0] = __builtin_amdgcn_mfma_f32_16x16x32_bf16(ah, b0h, acc[m][0], 0, 0, 0);
            acc[m][0] = __builtin_amdgcn_mfma_f32_16x16x32_bf16(ah, b0m, acc[m][0], 0, 0, 0);
            acc[m][0] = __builtin_amdgcn_mfma_f32_16x16x32_bf16(am, b0h, acc[m][0], 0, 0, 0);
            acc[m][0] = __builtin_amdgcn_mfma_f32_16x16x32_bf16(ah, b0l, acc[m][0], 0, 0, 0);
            acc[m][0] = __builtin_amdgcn_mfma_f32_16x16x32_bf16(al, b0h, acc[m][0], 0, 0, 0);
            acc[m][0] = __builtin_amdgcn_mfma_f32_16x16x32_bf16(am, b0m, acc[m][0], 0, 0, 0);
            acc[m][1] = __builtin_amdgcn_mfma_f32_16x16x32_bf16(ah, b1h, acc[m][1], 0, 0, 0);
            acc[m][1] = __builtin_amdgcn_mfma_f32_16x16x32_bf16(ah, b1m, acc[m][1], 0, 0, 0);
            acc[m][1] = __builtin_amdgcn_mfma_f32_16x16x32_bf16(am, b1h, acc[m][1], 0, 0, 0);
            acc[m][1] = __builtin_amdgcn_mfma_f32_16x16x32_bf16(ah, b1l, acc[m][1], 0, 0, 0);
            acc[m][1] = __builtin_amdgcn_mfma_f32_16x16x32_bf16(al, b1h, acc[m][1], 0, 0, 0);
            acc[m][1] = __builtin_amdgcn_mfma_f32_16x16x32_bf16(am, b1m, acc[m][1], 0, 0, 0);
        }
    }

    // C/D layout: col = lane&15, row = (lane>>4)*4 + reg   [m89-verified]
    #pragma unroll
    for (int m = 0; m < 8; ++m) {
        #pragma unroll
        for (int nf = 0; nf < 2; ++nf) {
            int col = c0 + nf * 16 + lo;
            if (col < N) {
                float bb = bias[col];
                #pragma unroll
                for (int r = 0; r < 4; ++r) {
                    int row = m * 16 + hi * 4 + r;
                    Z[(size_t)row * N + col] = acc[m][nf][r] + bb;
                }
            }
        }
    }
}

// ---------------------------------------------------------------------------
// Fused LN4 + gates + c-LN + zoneout.  Writes f32 h/c states AND the 3-plane
// bf16 split of the new h (consumed by the next rgemm3).  Optionally hist.
// ---------------------------------------------------------------------------
__device__ __forceinline__ float blockSum(float v, volatile float* red) {
    #pragma unroll
    for (int off = 32; off > 0; off >>= 1) v += __shfl_down(v, off, 64);
    int wid = threadIdx.x >> 6;
    int lane = threadIdx.x & 63;
    __syncthreads();
    if (lane == 0) red[wid] = v;
    __syncthreads();
    return red[0] + red[1] + red[2] + red[3];
}

#define MAXU 3
__global__ __launch_bounds__(256) void cell_pw(
    const float* __restrict__ z, int F,
    const float* __restrict__ gg, const float* __restrict__ bg,
    const float* __restrict__ gc, const float* __restrict__ bc,
    float* __restrict__ h, float* __restrict__ c,
    unsigned short* __restrict__ hpH, unsigned short* __restrict__ hpM,
    unsigned short* __restrict__ hpL, int hstride,
    unsigned short* __restrict__ hist, int t)
{
    __shared__ float red[8];
    const int b = blockIdx.x;
    const int tid = threadIdx.x;
    const float* zr = z + (size_t)b * 4 * F;
    float* hr = h + (size_t)b * F;
    float* cr = c + (size_t)b * F;

    float s[4] = {0, 0, 0, 0}, q[4] = {0, 0, 0, 0};
    for (int u = tid; u < F; u += 256) {
        #pragma unroll
        for (int g = 0; g < 4; ++g) { float v = zr[g * F + u]; s[g] += v; q[g] += v * v; }
    }
    float mu[4], rs[4];
    #pragma unroll
    for (int g = 0; g < 4; ++g) {
        float S = blockSum(s[g], red);
        float Q = blockSum(q[g], red);
        mu[g] = S / F;
        rs[g] = rsqrtf(Q / F - mu[g] * mu[g] + 1e-5f);
    }

    float nc[MAXU], og[MAXU], ho[MAXU], co[MAXU];
    float cs = 0.f, cq = 0.f;
    int nu = 0;
    for (int u = tid; u < F; u += 256) {
        float zi = (zr[u]         - mu[0]) * rs[0] * gg[u]         + bg[u];
        float zj = (zr[F + u]     - mu[1]) * rs[1] * gg[F + u]     + bg[F + u];
        float zf = (zr[2 * F + u] - mu[2]) * rs[2] * gg[2 * F + u] + bg[2 * F + u];
        float zo = (zr[3 * F + u] - mu[3]) * rs[3] * gg[3 * F + u] + bg[3 * F + u];
        float cold = cr[u];
        float ncv = cold * sigm(zf + 1.0f) + sigm(zi) * tanhf(zj);
        nc[nu] = ncv; og[nu] = sigm(zo); co[nu] = cold; ho[nu] = hr[u];
        cs += ncv; cq += ncv * ncv;
        ++nu;
    }
    float CS = blockSum(cs, red);
    float CQ = blockSum(cq, red);
    float muc = CS / F;
    float rsc = rsqrtf(CQ / F - muc * muc + 1e-5f);

    nu = 0;
    for (int u = tid; u < F; u += 256) {
        float nh = tanhf((nc[nu] - muc) * rsc * gc[u] + bc[u]) * og[nu];
        float hout = 0.9f * nh + 0.1f * ho[nu];
        float cout = 0.5f * nc[nu] + 0.5f * co[nu];
        hr[u] = hout;
        cr[u] = cout;
        unsigned short H, M, L;
        split3f(hout, H, M, L);
        size_t po = (size_t)b * hstride + u;
        hpH[po] = H; hpM[po] = M; hpL[po] = L;
        if (hist) hist[((size_t)b * T_ + t) * FP_ + u] = H;
        ++nu;
    }
}

// ---------------------------------------------------------------------------
// Output projection (plain bf16, no LDS): C = hist[12800,704] @ Wtout^T + bout
// 512 thr = 8 waves (4M x 2N), per-wave 64x64; fragments direct 16B loads.
// ---------------------------------------------------------------------------
__global__ __launch_bounds__(512) void ogemm(
    const unsigned short* __restrict__ A,     // hist [12800][704]
    const unsigned short* __restrict__ Bt,    // Wtout [10112][704]
    const float* __restrict__ bias,
    float* __restrict__ C)
{
    const int N = V_;
    const int tid = threadIdx.x, lane = tid & 63, wid = tid >> 6;
    const int wm = wid >> 1, wn = wid & 1;
    const int row0 = blockIdx.y * 256 + wm * 64;
    const int col0 = blockIdx.x * 128 + wn * 64;
    const int lo = lane & 15, hi = lane >> 4;
    const int NT = FP_ / 32;   // 22

    v4f acc[4][4];
    #pragma unroll
    for (int i = 0; i < 4; ++i)
        #pragma unroll
        for (int j = 0; j < 4; ++j) acc[i][j] = (v4f)0.f;

    for (int kt = 0; kt < NT; ++kt) {
        const int kb = kt * 32 + hi * 8;
        v8s a[4], b[4];
        #pragma unroll
        for (int i = 0; i < 4; ++i) {
            a[i] = *(const v8s*)(A  + (size_t)(row0 + i * 16 + lo) * FP_ + kb);
            b[i] = *(const v8s*)(Bt + (size_t)(col0 + i * 16 + lo) * FP_ + kb);
        }
        #pragma unroll
        for (int mf = 0; mf < 4; ++mf)
            #pragma unroll
            for (int nf = 0; nf < 4; ++nf)
                acc[mf][nf] = __builtin_amdgcn_mfma_f32_16x16x32_bf16(a[mf], b[nf], acc[mf][nf], 0, 0, 0);
    }

    #pragma unroll
    for (int mf = 0; mf < 4; ++mf) {
        #pragma unroll
        for (int nf = 0; nf < 4; ++nf) {
            int col = col0 + nf * 16 + lo;
            if (col < N) {
                float bb = bias[col];
                #pragma unroll
                for (int r = 0; r < 4; ++r) {
                    int row = row0 + mf * 16 + hi * 4 + r;
                    C[(size_t)row * N + col] = acc[mf][nf][r] + bb;
                }
            }
        }
    }
}

// Final states (fh, fc, sh, sc) -> tail of d_out.
__global__ void copy_states(const float* __restrict__ fh, const float* __restrict__ fc,
                            const float* __restrict__ sh, const float* __restrict__ sc,
                            float* __restrict__ out)
{
    int i = blockIdx.x * 256 + threadIdx.x;
    const int NF = B_ * F_, NS = B_ * S_;
    if (i < NF) out[i] = fh[i];
    else if (i < 2 * NF) out[i] = fc[i - NF];
    else if (i < 2 * NF + NS) out[i] = sh[i - 2 * NF];
    else if (i < 2 * NF + 2 * NS) out[i] = sc[i - 2 * NF - NS];
}

extern "C" void kernel_launch(void* const* d_in, const int* in_sizes, int n_in,
                              void* d_out, int out_size, void* d_ws, size_t ws_size,
                              hipStream_t stream) {
    const float* inputs = (const float*)d_in[0];
    const float* W0   = (const float*)d_in[1];
    const float* b0   = (const float*)d_in[2];
    const float* g0   = (const float*)d_in[3];
    const float* bg0  = (const float*)d_in[4];
    const float* gc0  = (const float*)d_in[5];
    const float* bc0  = (const float*)d_in[6];
    const float* W1   = (const float*)d_in[7];
    const float* b1   = (const float*)d_in[8];
    const float* g1   = (const float*)d_in[9];
    const float* bg1  = (const float*)d_in[10];
    const float* gc1  = (const float*)d_in[11];
    const float* bc1  = (const float*)d_in[12];
    const float* WS   = (const float*)d_in[13];
    const float* bS   = (const float*)d_in[14];
    const float* gS   = (const float*)d_in[15];
    const float* bgS  = (const float*)d_in[16];
    const float* gcS  = (const float*)d_in[17];
    const float* bcS  = (const float*)d_in[18];
    const float* Wout = (const float*)d_in[19];
    const float* bout = (const float*)d_in[20];

    // plane sizes (elements)
    const size_t P0 = (size_t)2816 * 832;     // W0 plane
    const size_t PS = (size_t)1664 * 1120;    // WS plane
    const size_t P1 = (size_t)2816 * 1120;    // W1 plane
    const size_t HF = (size_t)B_ * FP_;       // fh plane
    const size_t HS = (size_t)B_ * SP_;       // sh plane

    // ---- common ws prefix: f32 states + z + bf16 hist
    float* ws = (float*)d_ws;
    float* fh = ws;                           // 89600 f32
    float* fc = fh + B_ * F_;
    float* sh = fc + B_ * F_;
    float* sc = sh + B_ * S_;
    float* z  = sc + B_ * S_;                 // 358400 f32
    unsigned short* hist = (unsigned short*)(z + (size_t)B_ * 4 * F_);  // 12800*704
    unsigned short* after_hist = hist + (size_t)12800 * FP_;

    // ---- scratch placement: ws if it fits (65,605,632 B needed), else d_out.
    const bool big = ws_size >= 65700000ull;
    unsigned short *fhH, *fhM, *fhL, *shH, *shM, *shL;
    unsigned short *W0H, *W0M, *W0L, *WSH, *WSM, *WSL, *W1H, *W1M, *W1L;
    unsigned short *Wtout;
    if (big) {
        fhH = after_hist;   fhM = fhH + HF;  fhL = fhM + HF;
        shH = fhL + HF;     shM = shH + HS;  shL = shM + HS;
        W0H = shL + HS;     W0M = W0H + P0;  W0L = W0M + P0;
        WSH = W0L + P0;     WSM = WSH + PS;  WSL = WSM + PS;
        W1H = WSL + PS;     W1M = W1H + P1;  W1L = W1M + P1;
        Wtout = W0H;        // overlays W0+WS planes (dead after recurrence)
    } else {
        Wtout = after_hist; // ws (round-4 footprint, known-safe)
        unsigned short* dp = (unsigned short*)d_out;
        W0H = dp;           W0M = W0H + P0;  W0L = W0M + P0;
        WSH = W0L + P0;     WSM = WSH + PS;  WSL = WSM + PS;
        W1H = WSL + PS;     W1M = W1H + P1;  W1L = W1M + P1;
        fhH = W1L + P1;     fhM = fhH + HF;  fhL = fhM + HF;
        shH = fhL + HF;     shM = shH + HS;  shL = shM + HS;
    }

    // zero: f32 states; hist (pads); h planes (initial state + k-pads)
    hipMemsetAsync(fh, 0, (size_t)(2 * B_ * F_ + 2 * B_ * S_) * sizeof(float), stream);
    hipMemsetAsync(hist, 0, (size_t)12800 * FP_ * sizeof(unsigned short), stream);
    hipMemsetAsync(fhH, 0, (3 * HF + 3 * HS) * sizeof(unsigned short), stream);

    // weight transposes+splits (every scratch element written each call)
    wtrans3<<<dim3(88, 26), 256, 0, stream>>>(W0, E_ + F_, 4 * F_, W0H, W0M, W0L, 832, 128, 128);
    wtrans3<<<dim3(52, 35), 256, 0, stream>>>(WS, F_ + S_, 4 * S_, WSH, WSM, WSL, 1120, F_, FP_);
    wtrans3<<<dim3(88, 35), 256, 0, stream>>>(W1, S_ + F_, 4 * F_, W1H, W1M, W1L, 1120, S_, SP_);

    for (int t = 0; t < T_; ++t) {
        // cell 0: A = [x_t | fh], K = 128 + 704
        rgemm3<true><<<22, 256, 0, stream>>>(inputs + (size_t)t * E_,
                                             nullptr, nullptr, nullptr, T_ * E_, 128,
                                             fhH, fhM, fhL, FP_,
                                             W0H, W0M, W0L, 832, b0, z, 4 * F_);
        cell_pw<<<B_, 256, 0, stream>>>(z, F_, g0, bg0, gc0, bc0, fh, fc,
                                        fhH, fhM, fhL, FP_, nullptr, 0);
        // slow: A = [fh | sh], K = 704 + 416
        rgemm3<false><<<13, 256, 0, stream>>>(nullptr,
                                              fhH, fhM, fhL, FP_, FP_,
                                              shH, shM, shL, SP_,
                                              WSH, WSM, WSL, 1120, bS, z, 4 * S_);
        cell_pw<<<B_, 256, 0, stream>>>(z, S_, gS, bgS, gcS, bcS, sh, sc,
                                        shH, shM, shL, SP_, nullptr, 0);
        // cell 1: A = [sh | fh], K = 416 + 704
        rgemm3<false><<<22, 256, 0, stream>>>(nullptr,
                                              shH, shM, shL, SP_, SP_,
                                              fhH, fhM, fhL, FP_,
                                              W1H, W1M, W1L, 1120, b1, z, 4 * F_);
        cell_pw<<<B_, 256, 0, stream>>>(z, F_, g1, bg1, gc1, bc1, fh, fc,
                                        fhH, fhM, fhL, FP_, hist, t);
    }

    // Wout transpose AFTER the recurrence (Wtout may overlay dead W planes)
    wtrans<<<dim3(316, 22), 256, 0, stream>>>(Wout, F_, V_, Wtout, FP_);

    // logits
    ogemm<<<dim3(79, 50), 512, 0, stream>>>(hist, Wtout, bout, (float*)d_out);

    // final states
    copy_states<<<1100, 256, 0, stream>>>(fh, fc, sh, sc,
                                          (float*)d_out + (size_t)B_ * T_ * V_);
}

// Round 6
// 37898.819 us; speedup vs baseline: 1.1675x; 1.1208x over previous
//
#include <hip/hip_runtime.h>
#include <math.h>

// ---------------------------------------------------------------------------
// PTB LN-LSTM stack: B=128, T=100, E=128, F=700, S=400, V=10000.
// Round 6: single persistent mega-kernel for the whole recurrence (software
// grid barrier, device-scope atomics + threadfence), eliminating ~600
// dependent dispatches (~70 us each measured r1/r5). Split-precision 3-plane
// bf16 MFMA math is bit-identical to round 5 (absmax 0.03125 proven).
// Dispatches: memset(bar) + mega + ogemm.
// ---------------------------------------------------------------------------

#define B_ 128
#define T_ 100
#define E_ 128
#define F_ 700
#define S_ 400
#define V_ 10000

#define FP_ 704    // F padded to mult of 32
#define SP_ 416    // S padded to mult of 32
#define G_  128    // mega grid blocks (<= 256 CUs -> always co-resident)

using v8s = __attribute__((ext_vector_type(8))) short;   // 8 bf16 (4 VGPR)
using v4f = __attribute__((ext_vector_type(4))) float;   // MFMA acc
typedef unsigned short u16;

__device__ __forceinline__ u16 f2bf(float x) {
    unsigned int u = __float_as_uint(x);
    u += 0x7FFFu + ((u >> 16) & 1u);          // round-to-nearest-even
    return (u16)(u >> 16);
}
__device__ __forceinline__ float bf2f(u16 h) {
    return __uint_as_float(((unsigned int)h) << 16);
}
__device__ __forceinline__ void split3f(float x, u16& h, u16& m, u16& l) {
    h = f2bf(x); float r  = x - bf2f(h);
    m = f2bf(r); float r2 = r - bf2f(m);
    l = f2bf(r2);
}
__device__ __forceinline__ float sigm(float x) { return 1.0f / (1.0f + expf(-x)); }

// ---------------------------------------------------------------------------
// Grid barrier: sense-reversing, device-scope. bar[0]=count, bar[1]=gen.
// Co-residency guaranteed (G_ blocks <= 256 CUs, 1 block/CU min occupancy).
// ---------------------------------------------------------------------------
__device__ __forceinline__ void gbar(unsigned* bar) {
    __syncthreads();
    if (threadIdx.x == 0) {
        __threadfence();   // release prior writes (agent scope, cross-XCD)
        unsigned gen = __hip_atomic_load(bar + 1, __ATOMIC_RELAXED, __HIP_MEMORY_SCOPE_AGENT);
        unsigned old = __hip_atomic_fetch_add(bar, 1u, __ATOMIC_ACQ_REL, __HIP_MEMORY_SCOPE_AGENT);
        if (old == G_ - 1) {
            __hip_atomic_store(bar, 0u, __ATOMIC_RELAXED, __HIP_MEMORY_SCOPE_AGENT);
            __hip_atomic_fetch_add(bar + 1, 1u, __ATOMIC_RELEASE, __HIP_MEMORY_SCOPE_AGENT);
        } else {
            while (__hip_atomic_load(bar + 1, __ATOMIC_RELAXED, __HIP_MEMORY_SCOPE_AGENT) == gen)
                __builtin_amdgcn_s_sleep(1);
        }
        __threadfence();   // acquire side
    }
    __syncthreads();
}

// ---------------------------------------------------------------------------
// Cooperative tiled transpose+split: W[K][N] f32 -> H/M/L[Npad][Kp] bf16.
// Every (r,kpos) element in [Npad][Kp] is written (pads -> 0): replay-safe.
// k-remap: kpos<K1 -> kpos ; K1<=kpos<K1pad -> pad ; else K1+(kpos-K1pad).
// M==nullptr -> single-plane (Wout). Grid-strided over 32x32 tiles.
// ---------------------------------------------------------------------------
__device__ void trans_phase(const float* __restrict__ W, int K, int N,
                            u16* __restrict__ H, u16* __restrict__ M,
                            u16* __restrict__ L, int Kp, int Npad,
                            int K1, int K1pad, float (*tb)[33])
{
    const int nTx = Npad / 32, nTy = Kp / 32;
    const int tx = threadIdx.x & 31, ty = threadIdx.x >> 5;
    for (int tl = blockIdx.x; tl < nTx * nTy; tl += G_) {
        const int c0 = (tl % nTx) * 32, kp0 = (tl / nTx) * 32;
        #pragma unroll
        for (int i = 0; i < 4; ++i) {
            int kpos = kp0 + ty + i * 8, c = c0 + tx;
            int k = (kpos < K1) ? kpos : (kpos >= K1pad ? K1 + (kpos - K1pad) : -1);
            tb[ty + i * 8][tx] = (k >= 0 && k < K && c < N) ? W[(size_t)k * N + c] : 0.f;
        }
        __syncthreads();
        #pragma unroll
        for (int i = 0; i < 4; ++i) {
            int r = c0 + ty + i * 8;
            u16 h, m, l;
            split3f(tb[tx][ty + i * 8], h, m, l);
            size_t idx = (size_t)r * Kp + kp0 + tx;
            H[idx] = h;
            if (M) { M[idx] = m; L[idx] = l; }
        }
        __syncthreads();
    }
}

// ---------------------------------------------------------------------------
// GEMM phase: Z[128,N] = concat(A1,A2)[128,Kp] @ Wt^T + bias (3-plane,
// 6 MFMA products hh,hm,mh,hl,lh,mm -> ~2^-26 rel; order == round 5).
// Per-wave 128x16 output tile; tiles grid-strided over all G_*4 waves.
// XF32: A1 is raw f32 (inputs x), split 3-way in registers.
// ---------------------------------------------------------------------------
template <bool XF32>
__device__ void gemm_phase(
    const float* __restrict__ xA1,
    const u16* __restrict__ A1H, const u16* __restrict__ A1M,
    const u16* __restrict__ A1L, int lda1, int K1pad,
    const u16* __restrict__ A2H, const u16* __restrict__ A2M,
    const u16* __restrict__ A2L, int lda2,
    const u16* __restrict__ WH, const u16* __restrict__ WM,
    const u16* __restrict__ WL, int Kp,
    const float* __restrict__ bias, float* __restrict__ z, int N)
{
    const int lane = threadIdx.x & 63, wid = threadIdx.x >> 6;
    const int lo = lane & 15, hi = lane >> 4;
    const int NT = Kp / 32;
    for (int tile = blockIdx.x * 4 + wid; tile * 16 < N; tile += G_ * 4) {
        const int c0 = tile * 16;
        v4f acc[8];
        #pragma unroll
        for (int m = 0; m < 8; ++m) acc[m] = (v4f)0.f;
        const size_t bbase = (size_t)(c0 + lo) * Kp + hi * 8;
        for (int kt = 0; kt < NT; ++kt) {
            const size_t bo = bbase + kt * 32;
            v8s bh = *(const v8s*)(WH + bo);
            v8s bm = *(const v8s*)(WM + bo);
            v8s bl = *(const v8s*)(WL + bo);
            const bool s1 = (kt * 32) < K1pad;
            const int ko = s1 ? kt * 32 : kt * 32 - K1pad;
            #pragma unroll
            for (int m = 0; m < 8; ++m) {
                v8s ah, am, al;
                if (XF32 && s1) {
                    const float* p = xA1 + (size_t)(m * 16 + lo) * lda1 + ko + hi * 8;
                    float v0[8];
                    *(float4*)(v0)     = *(const float4*)(p);
                    *(float4*)(v0 + 4) = *(const float4*)(p + 4);
                    #pragma unroll
                    for (int j = 0; j < 8; ++j) {
                        u16 hh, mm, ll; split3f(v0[j], hh, mm, ll);
                        ah[j] = (short)hh; am[j] = (short)mm; al[j] = (short)ll;
                    }
                } else {
                    const u16* pH = s1 ? A1H : A2H;
                    const u16* pM = s1 ? A1M : A2M;
                    const u16* pL = s1 ? A1L : A2L;
                    const int lda = s1 ? lda1 : lda2;
                    size_t ao = (size_t)(m * 16 + lo) * lda + ko + hi * 8;
                    ah = *(const v8s*)(pH + ao);
                    am = *(const v8s*)(pM + ao);
                    al = *(const v8s*)(pL + ao);
                }
                acc[m] = __builtin_amdgcn_mfma_f32_16x16x32_bf16(ah, bh, acc[m], 0, 0, 0);
                acc[m] = __builtin_amdgcn_mfma_f32_16x16x32_bf16(ah, bm, acc[m], 0, 0, 0);
                acc[m] = __builtin_amdgcn_mfma_f32_16x16x32_bf16(am, bh, acc[m], 0, 0, 0);
                acc[m] = __builtin_amdgcn_mfma_f32_16x16x32_bf16(ah, bl, acc[m], 0, 0, 0);
                acc[m] = __builtin_amdgcn_mfma_f32_16x16x32_bf16(al, bh, acc[m], 0, 0, 0);
                acc[m] = __builtin_amdgcn_mfma_f32_16x16x32_bf16(am, bm, acc[m], 0, 0, 0);
            }
        }
        // C/D layout: col = lane&15, row = (lane>>4)*4 + reg  [m89-verified]
        const float bb = bias[c0 + lo];
        #pragma unroll
        for (int m = 0; m < 8; ++m) {
            #pragma unroll
            for (int r = 0; r < 4; ++r) {
                int row = m * 16 + hi * 4 + r;
                z[(size_t)row * N + c0 + lo] = acc[m][r] + bb;
            }
        }
    }
}

// Block-wide sum over 256 threads (4 waves), broadcast.
__device__ __forceinline__ float blockSum(float v, volatile float* red) {
    #pragma unroll
    for (int off = 32; off > 0; off >>= 1) v += __shfl_down(v, off, 64);
    int w = threadIdx.x >> 6;
    int lane = threadIdx.x & 63;
    __syncthreads();
    if (lane == 0) red[w] = v;
    __syncthreads();
    return red[0] + red[1] + red[2] + red[3];
}

// ---------------------------------------------------------------------------
// Pointwise phase: LN4 + gates + c-LN + zoneout for rows grid-strided over
// blocks (G_=128 -> 1 row/block). Statically unrolled (FF compile-time).
// Writes f32 h/c + 3-plane bf16 h split (+ hist incl. zeroed pad cols).
// ---------------------------------------------------------------------------
template <int FF>
__device__ void pw_phase(const float* __restrict__ z,
    const float* __restrict__ gg, const float* __restrict__ bg,
    const float* __restrict__ gc, const float* __restrict__ bc,
    float* __restrict__ h, float* __restrict__ c,
    u16* __restrict__ hpH, u16* __restrict__ hpM, u16* __restrict__ hpL,
    int hstride, u16* __restrict__ hist, int t, volatile float* red)
{
    const int tid = threadIdx.x;
    constexpr int NU = (FF + 255) / 256;
    for (int b = blockIdx.x; b < B_; b += G_) {
        const float* zr = z + (size_t)b * 4 * FF;
        float* hr = h + (size_t)b * FF;
        float* cr = c + (size_t)b * FF;

        float s[4] = {0, 0, 0, 0}, q[4] = {0, 0, 0, 0};
        #pragma unroll
        for (int i = 0; i < NU; ++i) {
            int u = tid + i * 256;
            if (u < FF) {
                #pragma unroll
                for (int g = 0; g < 4; ++g) { float v = zr[g * FF + u]; s[g] += v; q[g] += v * v; }
            }
        }
        float mu[4], rs[4];
        #pragma unroll
        for (int g = 0; g < 4; ++g) {
            float S = blockSum(s[g], red);
            float Q = blockSum(q[g], red);
            mu[g] = S / FF;
            rs[g] = rsqrtf(Q / FF - mu[g] * mu[g] + 1e-5f);
        }

        float nc[NU], og[NU], ho[NU], co[NU];
        float cs = 0.f, cq = 0.f;
        #pragma unroll
        for (int i = 0; i < NU; ++i) {
            int u = tid + i * 256;
            if (u < FF) {
                float zi = (zr[u]           - mu[0]) * rs[0] * gg[u]           + bg[u];
                float zj = (zr[FF + u]      - mu[1]) * rs[1] * gg[FF + u]      + bg[FF + u];
                float zf = (zr[2 * FF + u]  - mu[2]) * rs[2] * gg[2 * FF + u]  + bg[2 * FF + u];
                float zo = (zr[3 * FF + u]  - mu[3]) * rs[3] * gg[3 * FF + u]  + bg[3 * FF + u];
                float cold = cr[u];
                float ncv = cold * sigm(zf + 1.0f) + sigm(zi) * tanhf(zj);
                nc[i] = ncv; og[i] = sigm(zo); co[i] = cold; ho[i] = hr[u];
                cs += ncv; cq += ncv * ncv;
            } else { nc[i] = 0.f; og[i] = 0.f; co[i] = 0.f; ho[i] = 0.f; }
        }
        float CS = blockSum(cs, red);
        float CQ = blockSum(cq, red);
        float muc = CS / FF;
        float rsc = rsqrtf(CQ / FF - muc * muc + 1e-5f);

        #pragma unroll
        for (int i = 0; i < NU; ++i) {
            int u = tid + i * 256;
            if (u < FF) {
                float nh = tanhf((nc[i] - muc) * rsc * gc[u] + bc[u]) * og[i];
                float hout = 0.9f * nh + 0.1f * ho[i];
                float cout = 0.5f * nc[i] + 0.5f * co[i];
                hr[u] = hout;
                cr[u] = cout;
                u16 H, M, L;
                split3f(hout, H, M, L);
                size_t po = (size_t)b * hstride + u;
                hpH[po] = H; hpM[po] = M; hpL[po] = L;
                if (hist) hist[((size_t)b * T_ + t) * FP_ + u] = H;
            }
        }
        if (hist && tid < FP_ - FF)   // zero hist pad cols (replay-safe)
            hist[((size_t)b * T_ + t) * FP_ + FF + tid] = 0;
    }
}

// ---------------------------------------------------------------------------
// The mega-kernel: init -> 100 x (GEMM0|PW0|GEMMS|PWS|GEMM1|PW1) -> tail.
// ---------------------------------------------------------------------------
__global__ __launch_bounds__(256) void mega(
    const float* __restrict__ inputs,
    const float* __restrict__ W0, const float* __restrict__ b0,
    const float* __restrict__ g0, const float* __restrict__ bg0,
    const float* __restrict__ gc0, const float* __restrict__ bc0,
    const float* __restrict__ W1, const float* __restrict__ b1,
    const float* __restrict__ g1, const float* __restrict__ bg1,
    const float* __restrict__ gc1, const float* __restrict__ bc1,
    const float* __restrict__ WS, const float* __restrict__ bS,
    const float* __restrict__ gS, const float* __restrict__ bgS,
    const float* __restrict__ gcS, const float* __restrict__ bcS,
    const float* __restrict__ Wout,
    float* fh, float* fc, float* sh, float* sc, float* z, u16* hist,
    u16* fhH, u16* fhM, u16* fhL, u16* shH, u16* shM, u16* shL,
    u16* W0H, u16* W0M, u16* W0L, u16* WSH, u16* WSM, u16* WSL,
    u16* W1H, u16* W1M, u16* W1L, u16* Wtout,
    float* outTail, unsigned* bar)
{
    __shared__ float tbuf[32][33];
    __shared__ float red[8];
    const int gtid = blockIdx.x * 256 + threadIdx.x;

    // ---- init: zero states + h/s planes; transpose+split recurrent weights
    for (int i = gtid; i < 2 * B_ * F_ + 2 * B_ * S_; i += G_ * 256) fh[i] = 0.f;
    for (int i = gtid; i < 3 * B_ * FP_ + 3 * B_ * SP_; i += G_ * 256) fhH[i] = 0;
    trans_phase(W0, E_ + F_, 4 * F_, W0H, W0M, W0L, 832,  2816, 128, 128, tbuf);
    trans_phase(WS, F_ + S_, 4 * S_, WSH, WSM, WSL, 1120, 1664, F_,  FP_, tbuf);
    trans_phase(W1, S_ + F_, 4 * F_, W1H, W1M, W1L, 1120, 2816, S_,  SP_, tbuf);
    gbar(bar);

    for (int t = 0; t < T_; ++t) {
        gemm_phase<true>(inputs + (size_t)t * E_, nullptr, nullptr, nullptr, T_ * E_, 128,
                         fhH, fhM, fhL, FP_, W0H, W0M, W0L, 832, b0, z, 4 * F_);
        gbar(bar);
        pw_phase<F_>(z, g0, bg0, gc0, bc0, fh, fc, fhH, fhM, fhL, FP_, nullptr, 0, red);
        gbar(bar);
        gemm_phase<false>(nullptr, fhH, fhM, fhL, FP_, FP_, shH, shM, shL, SP_,
                          WSH, WSM, WSL, 1120, bS, z, 4 * S_);
        gbar(bar);
        pw_phase<S_>(z, gS, bgS, gcS, bcS, sh, sc, shH, shM, shL, SP_, nullptr, 0, red);
        gbar(bar);
        gemm_phase<false>(nullptr, shH, shM, shL, SP_, SP_, fhH, fhM, fhL, FP_,
                          W1H, W1M, W1L, 1120, b1, z, 4 * F_);
        gbar(bar);
        pw_phase<F_>(z, g1, bg1, gc1, bc1, fh, fc, fhH, fhM, fhL, FP_, hist, t, red);
        gbar(bar);
    }

    // ---- tail: Wout transpose (overlays dead W planes) + final states
    trans_phase(Wout, F_, V_, Wtout, nullptr, nullptr, FP_, 10112, F_, F_, tbuf);
    const int NF = B_ * F_, NS = B_ * S_;
    for (int i = gtid; i < 2 * NF + 2 * NS; i += G_ * 256) {
        float v = (i < NF) ? fh[i] : (i < 2 * NF) ? fc[i - NF]
                : (i < 2 * NF + NS) ? sh[i - 2 * NF] : sc[i - 2 * NF - NS];
        outTail[i] = v;
    }
}

// ---------------------------------------------------------------------------
// Output projection (round-5-proven, unchanged): C = hist @ Wtout^T + bout
// ---------------------------------------------------------------------------
__global__ __launch_bounds__(512) void ogemm(
    const u16* __restrict__ A,     // hist [12800][704]
    const u16* __restrict__ Bt,    // Wtout [10112][704]
    const float* __restrict__ bias,
    float* __restrict__ C)
{
    const int N = V_;
    const int tid = threadIdx.x, lane = tid & 63, wid = tid >> 6;
    const int wm = wid >> 1, wn = wid & 1;
    const int row0 = blockIdx.y * 256 + wm * 64;
    const int col0 = blockIdx.x * 128 + wn * 64;
    const int lo = lane & 15, hi = lane >> 4;
    const int NT = FP_ / 32;

    v4f acc[4][4];
    #pragma unroll
    for (int i = 0; i < 4; ++i)
        #pragma unroll
        for (int j = 0; j < 4; ++j) acc[i][j] = (v4f)0.f;

    for (int kt = 0; kt < NT; ++kt) {
        const int kb = kt * 32 + hi * 8;
        v8s a[4], b[4];
        #pragma unroll
        for (int i = 0; i < 4; ++i) {
            a[i] = *(const v8s*)(A  + (size_t)(row0 + i * 16 + lo) * FP_ + kb);
            b[i] = *(const v8s*)(Bt + (size_t)(col0 + i * 16 + lo) * FP_ + kb);
        }
        #pragma unroll
        for (int mf = 0; mf < 4; ++mf)
            #pragma unroll
            for (int nf = 0; nf < 4; ++nf)
                acc[mf][nf] = __builtin_amdgcn_mfma_f32_16x16x32_bf16(a[mf], b[nf], acc[mf][nf], 0, 0, 0);
    }

    #pragma unroll
    for (int mf = 0; mf < 4; ++mf) {
        #pragma unroll
        for (int nf = 0; nf < 4; ++nf) {
            int col = col0 + nf * 16 + lo;
            if (col < N) {
                float bb = bias[col];
                #pragma unroll
                for (int r = 0; r < 4; ++r) {
                    int row = row0 + mf * 16 + hi * 4 + r;
                    C[(size_t)row * N + col] = acc[mf][nf][r] + bb;
                }
            }
        }
    }
}

extern "C" void kernel_launch(void* const* d_in, const int* in_sizes, int n_in,
                              void* d_out, int out_size, void* d_ws, size_t ws_size,
                              hipStream_t stream) {
    const float* inputs = (const float*)d_in[0];
    const float* W0   = (const float*)d_in[1];
    const float* b0   = (const float*)d_in[2];
    const float* g0   = (const float*)d_in[3];
    const float* bg0  = (const float*)d_in[4];
    const float* gc0  = (const float*)d_in[5];
    const float* bc0  = (const float*)d_in[6];
    const float* W1   = (const float*)d_in[7];
    const float* b1   = (const float*)d_in[8];
    const float* g1   = (const float*)d_in[9];
    const float* bg1  = (const float*)d_in[10];
    const float* bc1_ = (const float*)d_in[12];
    const float* gc1  = (const float*)d_in[11];
    const float* WS   = (const float*)d_in[13];
    const float* bS   = (const float*)d_in[14];
    const float* gS   = (const float*)d_in[15];
    const float* bgS  = (const float*)d_in[16];
    const float* gcS  = (const float*)d_in[17];
    const float* bcS  = (const float*)d_in[18];
    const float* Wout = (const float*)d_in[19];
    const float* bout = (const float*)d_in[20];

    // plane sizes (elements)
    const size_t P0 = (size_t)2816 * 832;
    const size_t PS = (size_t)1664 * 1120;
    const size_t P1 = (size_t)2816 * 1120;
    const size_t HF = (size_t)B_ * FP_;
    const size_t HS = (size_t)B_ * SP_;

    // ---- ws prefix: f32 states + z + bf16 hist + barrier slot
    float* ws = (float*)d_ws;
    float* fh = ws;
    float* fc = fh + B_ * F_;
    float* sh = fc + B_ * F_;
    float* sc = sh + B_ * S_;
    float* z  = sc + B_ * S_;
    u16* hist = (u16*)(z + (size_t)B_ * 4 * F_);
    unsigned* bar = (unsigned*)(hist + (size_t)12800 * FP_);
    u16* scr = (u16*)((char*)bar + 64);

    // ---- scratch placement: ws if big enough, else d_out (fully written).
    const bool big = ws_size >= 65700000ull;
    u16 *fhH, *fhM, *fhL, *shH, *shM, *shL;
    u16 *W0H, *W0M, *W0L, *WSH, *WSM, *WSL, *W1H, *W1M, *W1L, *Wtout;
    if (big) {
        fhH = scr;        fhM = fhH + HF;  fhL = fhM + HF;
        shH = fhL + HF;   shM = shH + HS;  shL = shM + HS;
        W0H = shL + HS;   W0M = W0H + P0;  W0L = W0M + P0;
        WSH = W0L + P0;   WSM = WSH + PS;  WSL = WSM + PS;
        W1H = WSL + PS;   W1M = W1H + P1;  W1L = W1M + P1;
        Wtout = W0H;      // written in mega TAIL (W planes dead by then)
    } else {
        Wtout = scr;      // in ws (34.9 MB total, known-safe)
        u16* dp = (u16*)d_out;
        fhH = dp;         fhM = fhH + HF;  fhL = fhM + HF;
        shH = fhL + HF;   shM = shH + HS;  shL = shM + HS;
        W0H = shL + HS;   W0M = W0H + P0;  W0L = W0M + P0;
        WSH = W0L + P0;   WSM = WSH + PS;  WSL = WSM + PS;
        W1H = WSL + PS;   W1M = W1H + P1;  W1L = W1M + P1;
    }

    hipMemsetAsync(bar, 0, 8, stream);

    mega<<<G_, 256, 0, stream>>>(
        inputs,
        W0, b0, g0, bg0, gc0, bc0,
        W1, b1, g1, bg1, gc1, bc1_,
        WS, bS, gS, bgS, gcS, bcS,
        Wout,
        fh, fc, sh, sc, z, hist,
        fhH, fhM, fhL, shH, shM, shL,
        W0H, W0M, W0L, WSH, WSM, WSL, W1H, W1M, W1L, Wtout,
        (float*)d_out + (size_t)B_ * T_ * V_, bar);

    ogemm<<<dim3(79, 50), 512, 0, stream>>>(hist, Wtout, bout, (float*)d_out);
}